// Round 1
// baseline (63.419 us; speedup 1.0000x reference)
//
#include <hip/hip_runtime.h>

#define NUM_CENTERS 16

__device__ __forceinline__ float nearest_center(float v, const float* __restrict__ c) {
    // argmin over |v - c[i]|, first index wins ties (strict <), matching jnp.argmin
    float best_val = c[0];
    float best_d   = fabsf(v - c[0]);
#pragma unroll
    for (int i = 1; i < NUM_CENTERS; ++i) {
        float d = fabsf(v - c[i]);
        if (d < best_d) { best_d = d; best_val = c[i]; }
    }
    return best_val;
}

__global__ __launch_bounds__(256) void nearest_center_kernel(
    const float* __restrict__ x,
    const float* __restrict__ centers,
    float* __restrict__ out,
    int n4)  // number of float4 groups
{
    // Load centers into registers: wave-uniform addresses -> broadcast, L1/L2 cached.
    float c[NUM_CENTERS];
#pragma unroll
    for (int i = 0; i < NUM_CENTERS; ++i) c[i] = centers[i];

    int idx = blockIdx.x * blockDim.x + threadIdx.x;
    if (idx < n4) {
        float4 v = reinterpret_cast<const float4*>(x)[idx];
        float4 r;
        r.x = nearest_center(v.x, c);
        r.y = nearest_center(v.y, c);
        r.z = nearest_center(v.z, c);
        r.w = nearest_center(v.w, c);
        reinterpret_cast<float4*>(out)[idx] = r;
    }
}

extern "C" void kernel_launch(void* const* d_in, const int* in_sizes, int n_in,
                              void* d_out, int out_size, void* d_ws, size_t ws_size,
                              hipStream_t stream) {
    const float* x       = (const float*)d_in[0];   // (8,64,64,64) fp32, 2,097,152 elems
    const float* centers = (const float*)d_in[1];   // (16,) fp32
    float* out           = (float*)d_out;

    int n  = in_sizes[0];        // 2,097,152 (multiple of 4)
    int n4 = n / 4;              // 524,288 float4 groups

    const int block = 256;
    int grid = (n4 + block - 1) / block;  // 2048 blocks
    nearest_center_kernel<<<grid, block, 0, stream>>>(x, centers, out, n4);
}